// Round 1
// baseline (109.529 us; speedup 1.0000x reference)
//
#include <hip/hip_runtime.h>
#include <cstdint>
#include <cstddef>

#define TT  2048
#define HH  1024
#define FFN 2048
#define NL  4

typedef __attribute__((ext_vector_type(8))) short bf16x8;
typedef __attribute__((ext_vector_type(4))) float f32x4;

__device__ __forceinline__ unsigned short f2bf(float f) {
  unsigned u = __builtin_bit_cast(unsigned, f);
  u += 0x7FFFu + ((u >> 16) & 1u);           // round-to-nearest-even
  return (unsigned short)(u >> 16);
}

__device__ __forceinline__ bf16x8 pack8(f32x4 f0, f32x4 f1) {
  bf16x8 v;
  v[0] = (short)f2bf(f0[0]); v[1] = (short)f2bf(f0[1]);
  v[2] = (short)f2bf(f0[2]); v[3] = (short)f2bf(f0[3]);
  v[4] = (short)f2bf(f1[0]); v[5] = (short)f2bf(f1[1]);
  v[6] = (short)f2bf(f1[2]); v[7] = (short)f2bf(f1[3]);
  return v;
}

__device__ __forceinline__ void async16(void* lds, const void* g) {
  __builtin_amdgcn_global_load_lds(
      (const __attribute__((address_space(1))) unsigned int*)g,
      (__attribute__((address_space(3))) unsigned int*)lds, 16, 0, 0);
}

// ---------------------------------------------------------------- zero
__global__ void k_zero(float* __restrict__ out, int* __restrict__ cnt) {
  int i = blockIdx.x * 256 + threadIdx.x;     // grid 2048 -> 524288 threads
  f32x4 z = {0.f, 0.f, 0.f, 0.f};
  reinterpret_cast<f32x4*>(out)[i] = z;       // covers exactly T*H floats
  if (i < NL) cnt[i] = 0;
}

// ---------------------------------------------------------------- routing lists
__global__ void k_build(const int* __restrict__ sel, const float* __restrict__ rw,
                        int* __restrict__ cnt, int* __restrict__ tok,
                        float* __restrict__ wgt) {
  int t = blockIdx.x * 256 + threadIdx.x;
  if (t >= TT) return;
  int   s0 = sel[t*4+0], s1 = sel[t*4+1], s2 = sel[t*4+2], s3 = sel[t*4+3];
  float r0 = rw[t*4+0],  r1 = rw[t*4+1],  r2 = rw[t*4+2],  r3 = rw[t*4+3];
#pragma unroll
  for (int i = 0; i < NL; ++i) {
    int eid = i * 8;                           // LOCAL_EXPERT_IDS = 0,8,16,24
    float w = 0.f; bool m = false;
    if (s0 == eid) { w += r0; m = true; }
    if (s1 == eid) { w += r1; m = true; }
    if (s2 == eid) { w += r2; m = true; }
    if (s3 == eid) { w += r3; m = true; }
    if (m) {
      int p = atomicAdd(&cnt[i], 1);
      tok[i*TT + p] = t;
      wgt[i*TT + p] = w;
    }
  }
}

// ---------------------------------------------------------------- gather hidden -> bf16 compacted
__global__ void k_gather(const float* __restrict__ hidden, const int* __restrict__ cnt,
                         const int* __restrict__ tok, unsigned short* __restrict__ X) {
  int p = blockIdx.x, e = blockIdx.y;
  if (p >= cnt[e]) return;
  int t = tok[e*TT + p];
  const f32x4* src = reinterpret_cast<const f32x4*>(hidden + (size_t)t * HH);
  f32x4 a = src[threadIdx.x*2], b = src[threadIdx.x*2 + 1];
  reinterpret_cast<bf16x8*>(X + ((size_t)e*TT + p) * HH)[threadIdx.x] = pack8(a, b);
}

// ---------------------------------------------------------------- GEMM1: gu = X @ gate_up^T, h = silu(g)*u
// BM=128, BN=64 (gate cols; up cols mirrored), BK=32, 256 thr = 4 waves (2x2)
__global__ __launch_bounds__(256) void k_gemm1(
    const unsigned short* __restrict__ X, const float* __restrict__ gup,
    const int* __restrict__ cnt, unsigned short* __restrict__ Hb) {
  int e  = blockIdx.z;
  int c  = cnt[e];
  int m0 = blockIdx.y * 128;
  if (m0 >= c) return;
  int n0 = blockIdx.x * 64;

  __shared__ alignas(16) unsigned short As[128 * 32];
  __shared__ alignas(16) unsigned short Bg[64 * 32];
  __shared__ alignas(16) unsigned short Bu[64 * 32];

  int tid  = threadIdx.x;
  int lane = tid & 63, wv = tid >> 6;
  int lr = lane & 15,  lk = lane >> 4;
  int wr = wv >> 1,    wc = wv & 1;

  const unsigned short* Ab = X   + (size_t)e * TT * HH;
  const float*          Gb = gup + (size_t)e * 2 * FFN * HH;

  int rb = tid >> 2;            // 0..63 (B row in tile)
  int cb = (tid & 3) * 8;       // 0/8/16/24 (B col group)
  const float* gG = Gb + (size_t)(n0 + rb) * HH + cb;
  const float* gU = Gb + (size_t)(FFN + n0 + rb) * HH + cb;

  f32x4 accg[4][2], accu[4][2];
  f32x4 z = {0.f, 0.f, 0.f, 0.f};
#pragma unroll
  for (int a = 0; a < 4; ++a)
#pragma unroll
    for (int b = 0; b < 2; ++b) { accg[a][b] = z; accu[a][b] = z; }

  for (int k0 = 0; k0 < HH; k0 += 32) {
    __syncthreads();
    // A: 128x32 bf16 tile, 8KB, direct-to-LDS, 2 chunks of 1KB per wave
#pragma unroll
    for (int cc = 0; cc < 2; ++cc) {
      int chunk = (wv * 2 + cc) * 1024;
      int pos   = chunk + lane * 16;
      int row   = pos >> 6, colb = pos & 63;
      async16((char*)As + chunk,
              (const char*)(Ab + (size_t)(m0 + row) * HH + k0) + colb);
    }
    // B: convert fp32 -> bf16 in regs, gate rows and up rows
    {
      f32x4 f0 = *(const f32x4*)(gG + k0);
      f32x4 f1 = *(const f32x4*)(gG + k0 + 4);
      *(bf16x8*)(&Bg[rb * 32 + cb]) = pack8(f0, f1);
      f32x4 g0 = *(const f32x4*)(gU + k0);
      f32x4 g1 = *(const f32x4*)(gU + k0 + 4);
      *(bf16x8*)(&Bu[rb * 32 + cb]) = pack8(g0, g1);
    }
    __syncthreads();

    bf16x8 af[4], bgf[2], buf2[2];
#pragma unroll
    for (int mi = 0; mi < 4; ++mi)
      af[mi] = *(const bf16x8*)(&As[(wr * 64 + mi * 16 + lr) * 32 + lk * 8]);
#pragma unroll
    for (int ni = 0; ni < 2; ++ni) {
      bgf[ni]  = *(const bf16x8*)(&Bg[(wc * 32 + ni * 16 + lr) * 32 + lk * 8]);
      buf2[ni] = *(const bf16x8*)(&Bu[(wc * 32 + ni * 16 + lr) * 32 + lk * 8]);
    }
#pragma unroll
    for (int mi = 0; mi < 4; ++mi)
#pragma unroll
      for (int ni = 0; ni < 2; ++ni) {
        accg[mi][ni] = __builtin_amdgcn_mfma_f32_16x16x32_bf16(af[mi], bgf[ni],  accg[mi][ni], 0, 0, 0);
        accu[mi][ni] = __builtin_amdgcn_mfma_f32_16x16x32_bf16(af[mi], buf2[ni], accu[mi][ni], 0, 0, 0);
      }
  }

  // epilogue: h = silu(gate) * up -> bf16 Hbuf[e][p][col]
#pragma unroll
  for (int mi = 0; mi < 4; ++mi)
#pragma unroll
    for (int ni = 0; ni < 2; ++ni) {
      f32x4 g = accg[mi][ni], u = accu[mi][ni];
#pragma unroll
      for (int j = 0; j < 4; ++j) {
        int p = m0 + wr * 64 + mi * 16 + lk * 4 + j;
        if (p < c) {
          float gv = g[j];
          float hv = (gv / (1.f + __expf(-gv))) * u[j];
          int col = n0 + wc * 32 + ni * 16 + lr;
          Hb[((size_t)e * TT + p) * FFN + col] = f2bf(hv);
        }
      }
    }
}

// ---------------------------------------------------------------- GEMM2: out += w * (h @ down^T)
// BM=64, BN=64, BK=32, 256 thr = 4 waves (2x2), K=FFN
__global__ __launch_bounds__(256) void k_gemm2(
    const unsigned short* __restrict__ Hb, const float* __restrict__ down,
    const int* __restrict__ cnt, const int* __restrict__ tok,
    const float* __restrict__ wgt, float* __restrict__ out) {
  int e  = blockIdx.z;
  int c  = cnt[e];
  int m0 = blockIdx.y * 64;
  if (m0 >= c) return;
  int n0 = blockIdx.x * 64;

  __shared__ alignas(16) unsigned short As[64 * 32];
  __shared__ alignas(16) unsigned short Bs[64 * 32];

  int tid  = threadIdx.x;
  int lane = tid & 63, wv = tid >> 6;
  int lr = lane & 15,  lk = lane >> 4;
  int wr = wv >> 1,    wc = wv & 1;

  const unsigned short* Ab = Hb   + (size_t)e * TT * FFN;
  const float*          Db = down + (size_t)e * HH * FFN;

  int rb = tid >> 2, cb = (tid & 3) * 8;
  const float* gD = Db + (size_t)(n0 + rb) * FFN + cb;

  f32x4 acc[2][2];
  f32x4 z = {0.f, 0.f, 0.f, 0.f};
#pragma unroll
  for (int a = 0; a < 2; ++a)
#pragma unroll
    for (int b = 0; b < 2; ++b) acc[a][b] = z;

  for (int k0 = 0; k0 < FFN; k0 += 32) {
    __syncthreads();
    {
      int chunk = wv * 1024;                 // 4KB tile, 1 chunk per wave
      int pos   = chunk + lane * 16;
      int row   = pos >> 6, colb = pos & 63;
      async16((char*)As + chunk,
              (const char*)(Ab + (size_t)(m0 + row) * FFN + k0) + colb);
    }
    {
      f32x4 f0 = *(const f32x4*)(gD + k0);
      f32x4 f1 = *(const f32x4*)(gD + k0 + 4);
      *(bf16x8*)(&Bs[rb * 32 + cb]) = pack8(f0, f1);
    }
    __syncthreads();

    bf16x8 af[2], bf_[2];
#pragma unroll
    for (int mi = 0; mi < 2; ++mi)
      af[mi] = *(const bf16x8*)(&As[(wr * 32 + mi * 16 + lr) * 32 + lk * 8]);
#pragma unroll
    for (int ni = 0; ni < 2; ++ni)
      bf_[ni] = *(const bf16x8*)(&Bs[(wc * 32 + ni * 16 + lr) * 32 + lk * 8]);
#pragma unroll
    for (int mi = 0; mi < 2; ++mi)
#pragma unroll
      for (int ni = 0; ni < 2; ++ni)
        acc[mi][ni] = __builtin_amdgcn_mfma_f32_16x16x32_bf16(af[mi], bf_[ni], acc[mi][ni], 0, 0, 0);
  }

#pragma unroll
  for (int mi = 0; mi < 2; ++mi)
#pragma unroll
    for (int ni = 0; ni < 2; ++ni)
#pragma unroll
      for (int j = 0; j < 4; ++j) {
        int p = m0 + wr * 32 + mi * 16 + lk * 4 + j;
        if (p < c) {
          int   t = tok[e*TT + p];
          float w = wgt[e*TT + p];
          int col = n0 + wc * 32 + ni * 16 + lr;
          atomicAdd(&out[(size_t)t * HH + col], w * acc[mi][ni][j]);
        }
      }
}

// ---------------------------------------------------------------- launch
extern "C" void kernel_launch(void* const* d_in, const int* in_sizes, int n_in,
                              void* d_out, int out_size, void* d_ws, size_t ws_size,
                              hipStream_t stream) {
  const float* hidden = (const float*)d_in[0];
  const int*   sel    = (const int*)d_in[1];
  const float* rw     = (const float*)d_in[2];
  const float* gup    = (const float*)d_in[3];
  const float* dwn    = (const float*)d_in[4];
  float* out = (float*)d_out;

  char* ws = (char*)d_ws;
  int*            cnt = (int*)ws;                                    // 16 B (pad to 1 KB)
  int*            tok = (int*)(ws + 1024);                           // NL*TT*4 = 32 KB
  float*          wgt = (float*)(ws + 1024 + NL*TT*4);               // 32 KB
  unsigned short* X   = (unsigned short*)(ws + 66560);               // NL*TT*HH*2 = 16 MB
  unsigned short* Hb  = (unsigned short*)(ws + 66560 + (size_t)NL*TT*HH*2); // NL*TT*FFN*2 = 32 MB

  k_zero  <<<2048, 256, 0, stream>>>(out, cnt);
  k_build <<<8,    256, 0, stream>>>(sel, rw, cnt, tok, wgt);
  k_gather<<<dim3(TT, NL), 128, 0, stream>>>(hidden, cnt, tok, X);
  k_gemm1 <<<dim3(FFN/64, TT/128, NL), 256, 0, stream>>>(X, gup, cnt, Hb);
  k_gemm2 <<<dim3(HH/64, TT/64, NL), 256, 0, stream>>>(Hb, dwn, cnt, tok, wgt, out);
}

// Round 2
// 83.057 us; speedup vs baseline: 1.3187x; 1.3187x over previous
//
#include <hip/hip_runtime.h>
#include <cstdint>
#include <cstddef>

#define TT  2048
#define HH  1024
#define FFN 2048
#define NL  4
#define BK  64
#define SK  4            // split-K factor for gemm2 (K chunk = FFN/SK = 512)

typedef __attribute__((ext_vector_type(8))) short bf16x8;
typedef __attribute__((ext_vector_type(4))) float f32x4;

__device__ __forceinline__ unsigned short f2bf(float f) {
  unsigned u = __builtin_bit_cast(unsigned, f);
  u += 0x7FFFu + ((u >> 16) & 1u);           // round-to-nearest-even
  return (unsigned short)(u >> 16);
}

__device__ __forceinline__ bf16x8 pack8(f32x4 f0, f32x4 f1) {
  bf16x8 v;
  v[0] = (short)f2bf(f0[0]); v[1] = (short)f2bf(f0[1]);
  v[2] = (short)f2bf(f0[2]); v[3] = (short)f2bf(f0[3]);
  v[4] = (short)f2bf(f1[0]); v[5] = (short)f2bf(f1[1]);
  v[6] = (short)f2bf(f1[2]); v[7] = (short)f2bf(f1[3]);
  return v;
}

__device__ __forceinline__ void async16(void* lds, const void* g) {
  __builtin_amdgcn_global_load_lds(
      (const __attribute__((address_space(1))) unsigned int*)g,
      (__attribute__((address_space(3))) unsigned int*)lds, 16, 0, 0);
}

// XOR swizzle within a [rows][64 bf16] tile (128 B rows): spreads the 16-way
// column-bank alias across 8 distinct 16B slots. Involution (rule 21).
__device__ __forceinline__ int swz(int b) { return b ^ (((b >> 7) & 7) << 4); }

// ---------------------------------------------------------------- zero
__global__ void k_zero(float* __restrict__ out, int* __restrict__ cnt) {
  int i = blockIdx.x * 256 + threadIdx.x;     // 2048 blocks -> exactly T*H floats
  f32x4 z = {0.f, 0.f, 0.f, 0.f};
  reinterpret_cast<f32x4*>(out)[i] = z;
  if (i < NL) cnt[i] = 0;
}

// ---------------------------------------------------------------- routing lists
__global__ void k_build(const int* __restrict__ sel, const float* __restrict__ rw,
                        int* __restrict__ cnt, int* __restrict__ tok,
                        float* __restrict__ wgt) {
  int t = blockIdx.x * 256 + threadIdx.x;
  if (t >= TT) return;
  int   s0 = sel[t*4+0], s1 = sel[t*4+1], s2 = sel[t*4+2], s3 = sel[t*4+3];
  float r0 = rw[t*4+0],  r1 = rw[t*4+1],  r2 = rw[t*4+2],  r3 = rw[t*4+3];
#pragma unroll
  for (int i = 0; i < NL; ++i) {
    int eid = i * 8;                           // LOCAL_EXPERT_IDS = 0,8,16,24
    float w = 0.f; bool m = false;
    if (s0 == eid) { w += r0; m = true; }
    if (s1 == eid) { w += r1; m = true; }
    if (s2 == eid) { w += r2; m = true; }
    if (s3 == eid) { w += r3; m = true; }
    if (m) {
      int p = atomicAdd(&cnt[i], 1);
      tok[i*TT + p] = t;
      wgt[i*TT + p] = w;
    }
  }
}

// ---------------------------------------------------------------- gather hidden -> bf16 compacted
__global__ void k_gather(const float* __restrict__ hidden, const int* __restrict__ cnt,
                         const int* __restrict__ tok, unsigned short* __restrict__ X) {
  int p = blockIdx.x, e = blockIdx.y;
  if (p >= cnt[e]) return;
  int t = tok[e*TT + p];
  const f32x4* src = reinterpret_cast<const f32x4*>(hidden + (size_t)t * HH);
  f32x4 a = src[threadIdx.x*2], b = src[threadIdx.x*2 + 1];
  reinterpret_cast<bf16x8*>(X + ((size_t)e*TT + p) * HH)[threadIdx.x] = pack8(a, b);
}

// ---------------------------------------------------------------- GEMM1
// gu = X @ gate_up^T, h = silu(g)*u -> bf16 Hb
// BM=64, BN=64, BK=64, 256 thr = 4 waves (2x2); dual accumulators (gate+up).
// Double-buffered 2-phase: prefetch A via global_load_lds (pre-swizzled src),
// B fp32 loads into regs early, pack+ds_write after compute.
__global__ __launch_bounds__(256) void k_gemm1(
    const unsigned short* __restrict__ X, const float* __restrict__ gup,
    const int* __restrict__ cnt, unsigned short* __restrict__ Hb) {
  int e  = blockIdx.z;
  int c  = cnt[e];
  int m0 = blockIdx.y * 64;
  if (m0 >= c) return;
  int n0 = blockIdx.x * 64;

  __shared__ alignas(16) unsigned short As[2][64*64];
  __shared__ alignas(16) unsigned short Bg[2][64*64];
  __shared__ alignas(16) unsigned short Bu[2][64*64];

  int tid  = threadIdx.x;
  int lane = tid & 63, wv = tid >> 6;
  int lr = lane & 15,  lk = lane >> 4;
  int wr = wv >> 1,    wc = wv & 1;

  const unsigned short* Ab = X   + (size_t)e * TT * HH;
  const float*          Gb = gup + (size_t)e * 2 * FFN * HH;

  // A staging: 8 KB tile = 8 x 1KB chunks, 2 per wave; linear LDS dest,
  // pre-swizzled global source (rule 21).
  int P0 = (wv*2+0)*1024 + lane*16;
  int P1 = (wv*2+1)*1024 + lane*16;
  int ar0 = P0 >> 7, ac0 = (P0 & 127) ^ ((ar0 & 7) << 4);
  int ar1 = P1 >> 7, ac1 = (P1 & 127) ^ ((ar1 & 7) << 4);
  const char* srcA0 = (const char*)(Ab + (size_t)(m0 + ar0) * HH) + ac0;
  const char* srcA1 = (const char*)(Ab + (size_t)(m0 + ar1) * HH) + ac1;
  char* dstA0 = (char*)nullptr; // set per buffer below

  // B staging: thread owns 16 floats of one row: row rb, float col cbf..cbf+15
  int rb  = tid >> 2;
  int cbf = (tid & 3) * 16;
  const float* gG = Gb + (size_t)(n0 + rb) * HH + cbf;
  const float* gU = Gb + (size_t)(FFN + n0 + rb) * HH + cbf;
  int wb0 = swz(rb * 128 + cbf * 2);
  int wb1 = swz(rb * 128 + cbf * 2 + 16);

  // ds_read fragment offsets (per-thread constants)
  int aoff[2][2], boff[2][2];
#pragma unroll
  for (int mi = 0; mi < 2; ++mi)
#pragma unroll
    for (int kk = 0; kk < 2; ++kk)
      aoff[mi][kk] = swz((wr*32 + mi*16 + lr) * 128 + kk*64 + lk*16);
#pragma unroll
  for (int ni = 0; ni < 2; ++ni)
#pragma unroll
    for (int kk = 0; kk < 2; ++kk)
      boff[ni][kk] = swz((wc*32 + ni*16 + lr) * 128 + kk*64 + lk*16);

  f32x4 accg[2][2], accu[2][2];
  f32x4 z = {0.f, 0.f, 0.f, 0.f};
#pragma unroll
  for (int a = 0; a < 2; ++a)
#pragma unroll
    for (int b = 0; b < 2; ++b) { accg[a][b] = z; accu[a][b] = z; }

  f32x4 bgr[4], bur[4];

  // ---- prologue: stage tile 0 into buffer 0
  async16((char*)As[0] + (wv*2+0)*1024, srcA0);
  async16((char*)As[0] + (wv*2+1)*1024, srcA1);
#pragma unroll
  for (int i = 0; i < 4; ++i) {
    bgr[i] = *(const f32x4*)(gG + i*4);
    bur[i] = *(const f32x4*)(gU + i*4);
  }
  *(bf16x8*)((char*)Bg[0] + wb0) = pack8(bgr[0], bgr[1]);
  *(bf16x8*)((char*)Bg[0] + wb1) = pack8(bgr[2], bgr[3]);
  *(bf16x8*)((char*)Bu[0] + wb0) = pack8(bur[0], bur[1]);
  *(bf16x8*)((char*)Bu[0] + wb1) = pack8(bur[2], bur[3]);
  __syncthreads();   // compiler drains vmcnt+lgkm before s_barrier (m97)

  const int nt = HH / BK;   // 16
  int cur = 0;
  for (int t = 0; t < nt; ++t) {
    bool pre = (t + 1 < nt);
    if (pre) {
      int k0 = (t + 1) * BK;
      async16((char*)As[cur^1] + (wv*2+0)*1024, srcA0 + k0*2);
      async16((char*)As[cur^1] + (wv*2+1)*1024, srcA1 + k0*2);
#pragma unroll
      for (int i = 0; i < 4; ++i) {
        bgr[i] = *(const f32x4*)(gG + k0 + i*4);
        bur[i] = *(const f32x4*)(gU + k0 + i*4);
      }
    }
    // ---- compute tile cur
    bf16x8 af[2][2], bg_[2][2], bu_[2][2];
#pragma unroll
    for (int mi = 0; mi < 2; ++mi)
#pragma unroll
      for (int kk = 0; kk < 2; ++kk)
        af[mi][kk] = *(const bf16x8*)((const char*)As[cur] + aoff[mi][kk]);
#pragma unroll
    for (int ni = 0; ni < 2; ++ni)
#pragma unroll
      for (int kk = 0; kk < 2; ++kk) {
        bg_[ni][kk] = *(const bf16x8*)((const char*)Bg[cur] + boff[ni][kk]);
        bu_[ni][kk] = *(const bf16x8*)((const char*)Bu[cur] + boff[ni][kk]);
      }
#pragma unroll
    for (int kk = 0; kk < 2; ++kk)
#pragma unroll
      for (int mi = 0; mi < 2; ++mi)
#pragma unroll
        for (int ni = 0; ni < 2; ++ni) {
          accg[mi][ni] = __builtin_amdgcn_mfma_f32_16x16x32_bf16(af[mi][kk], bg_[ni][kk], accg[mi][ni], 0, 0, 0);
          accu[mi][ni] = __builtin_amdgcn_mfma_f32_16x16x32_bf16(af[mi][kk], bu_[ni][kk], accu[mi][ni], 0, 0, 0);
        }
    if (pre) {
      *(bf16x8*)((char*)Bg[cur^1] + wb0) = pack8(bgr[0], bgr[1]);
      *(bf16x8*)((char*)Bg[cur^1] + wb1) = pack8(bgr[2], bgr[3]);
      *(bf16x8*)((char*)Bu[cur^1] + wb0) = pack8(bur[0], bur[1]);
      *(bf16x8*)((char*)Bu[cur^1] + wb1) = pack8(bur[2], bur[3]);
      __syncthreads();
    }
    cur ^= 1;
  }

  // ---- epilogue: h = silu(gate) * up -> bf16 Hb[e][p][col]
#pragma unroll
  for (int mi = 0; mi < 2; ++mi)
#pragma unroll
    for (int ni = 0; ni < 2; ++ni) {
      f32x4 g = accg[mi][ni], u = accu[mi][ni];
#pragma unroll
      for (int j = 0; j < 4; ++j) {
        int p = m0 + wr*32 + mi*16 + lk*4 + j;
        if (p < c) {
          float gv = g[j];
          float hv = (gv / (1.f + __expf(-gv))) * u[j];
          int col = n0 + wc*32 + ni*16 + lr;
          Hb[((size_t)e * TT + p) * FFN + col] = f2bf(hv);
        }
      }
    }
}

// ---------------------------------------------------------------- GEMM2
// out += w * (h @ down^T); BM=64, BN=64, BK=64, split-K=4, 4 waves (2x2).
__global__ __launch_bounds__(256) void k_gemm2(
    const unsigned short* __restrict__ Hb, const float* __restrict__ down,
    const int* __restrict__ cnt, const int* __restrict__ tok,
    const float* __restrict__ wgt, float* __restrict__ out) {
  int zz = blockIdx.z;
  int sk = zz & (SK - 1);
  int e  = zz >> 2;                  // SK==4
  int c  = cnt[e];
  int m0 = blockIdx.y * 64;
  if (m0 >= c) return;
  int n0 = blockIdx.x * 64;
  int kbase = sk * (FFN / SK);       // 512-wide K chunk

  __shared__ alignas(16) unsigned short As[2][64*64];
  __shared__ alignas(16) unsigned short Bs[2][64*64];

  int tid  = threadIdx.x;
  int lane = tid & 63, wv = tid >> 6;
  int lr = lane & 15,  lk = lane >> 4;
  int wr = wv >> 1,    wc = wv & 1;

  const unsigned short* Ab = Hb   + (size_t)e * TT * FFN;
  const float*          Db = down + (size_t)e * HH * FFN;

  int P0 = (wv*2+0)*1024 + lane*16;
  int P1 = (wv*2+1)*1024 + lane*16;
  int ar0 = P0 >> 7, ac0 = (P0 & 127) ^ ((ar0 & 7) << 4);
  int ar1 = P1 >> 7, ac1 = (P1 & 127) ^ ((ar1 & 7) << 4);
  const char* srcA0 = (const char*)(Ab + (size_t)(m0 + ar0) * FFN + kbase) + ac0;
  const char* srcA1 = (const char*)(Ab + (size_t)(m0 + ar1) * FFN + kbase) + ac1;

  int rb  = tid >> 2;
  int cbf = (tid & 3) * 16;
  const float* gD = Db + (size_t)(n0 + rb) * FFN + kbase + cbf;
  int wb0 = swz(rb * 128 + cbf * 2);
  int wb1 = swz(rb * 128 + cbf * 2 + 16);

  int aoff[2][2], boff[2][2];
#pragma unroll
  for (int mi = 0; mi < 2; ++mi)
#pragma unroll
    for (int kk = 0; kk < 2; ++kk)
      aoff[mi][kk] = swz((wr*32 + mi*16 + lr) * 128 + kk*64 + lk*16);
#pragma unroll
  for (int ni = 0; ni < 2; ++ni)
#pragma unroll
    for (int kk = 0; kk < 2; ++kk)
      boff[ni][kk] = swz((wc*32 + ni*16 + lr) * 128 + kk*64 + lk*16);

  f32x4 acc[2][2];
  f32x4 z = {0.f, 0.f, 0.f, 0.f};
#pragma unroll
  for (int a = 0; a < 2; ++a)
#pragma unroll
    for (int b = 0; b < 2; ++b) acc[a][b] = z;

  f32x4 br[4];

  // ---- prologue
  async16((char*)As[0] + (wv*2+0)*1024, srcA0);
  async16((char*)As[0] + (wv*2+1)*1024, srcA1);
#pragma unroll
  for (int i = 0; i < 4; ++i) br[i] = *(const f32x4*)(gD + i*4);
  *(bf16x8*)((char*)Bs[0] + wb0) = pack8(br[0], br[1]);
  *(bf16x8*)((char*)Bs[0] + wb1) = pack8(br[2], br[3]);
  __syncthreads();

  const int nt = (FFN / SK) / BK;    // 8
  int cur = 0;
  for (int t = 0; t < nt; ++t) {
    bool pre = (t + 1 < nt);
    if (pre) {
      int k0 = (t + 1) * BK;
      async16((char*)As[cur^1] + (wv*2+0)*1024, srcA0 + k0*2);
      async16((char*)As[cur^1] + (wv*2+1)*1024, srcA1 + k0*2);
#pragma unroll
      for (int i = 0; i < 4; ++i) br[i] = *(const f32x4*)(gD + k0 + i*4);
    }
    bf16x8 af[2][2], bf_[2][2];
#pragma unroll
    for (int mi = 0; mi < 2; ++mi)
#pragma unroll
      for (int kk = 0; kk < 2; ++kk)
        af[mi][kk] = *(const bf16x8*)((const char*)As[cur] + aoff[mi][kk]);
#pragma unroll
    for (int ni = 0; ni < 2; ++ni)
#pragma unroll
      for (int kk = 0; kk < 2; ++kk)
        bf_[ni][kk] = *(const bf16x8*)((const char*)Bs[cur] + boff[ni][kk]);
#pragma unroll
    for (int kk = 0; kk < 2; ++kk)
#pragma unroll
      for (int mi = 0; mi < 2; ++mi)
#pragma unroll
        for (int ni = 0; ni < 2; ++ni)
          acc[mi][ni] = __builtin_amdgcn_mfma_f32_16x16x32_bf16(af[mi][kk], bf_[ni][kk], acc[mi][ni], 0, 0, 0);
    if (pre) {
      *(bf16x8*)((char*)Bs[cur^1] + wb0) = pack8(br[0], br[1]);
      *(bf16x8*)((char*)Bs[cur^1] + wb1) = pack8(br[2], br[3]);
      __syncthreads();
    }
    cur ^= 1;
  }

#pragma unroll
  for (int mi = 0; mi < 2; ++mi)
#pragma unroll
    for (int ni = 0; ni < 2; ++ni)
#pragma unroll
      for (int j = 0; j < 4; ++j) {
        int p = m0 + wr*32 + mi*16 + lk*4 + j;
        if (p < c) {
          int   t = tok[e*TT + p];
          float w = wgt[e*TT + p];
          int col = n0 + wc*32 + ni*16 + lr;
          atomicAdd(&out[(size_t)t * HH + col], w * acc[mi][ni][j]);
        }
      }
}

// ---------------------------------------------------------------- launch
extern "C" void kernel_launch(void* const* d_in, const int* in_sizes, int n_in,
                              void* d_out, int out_size, void* d_ws, size_t ws_size,
                              hipStream_t stream) {
  const float* hidden = (const float*)d_in[0];
  const int*   sel    = (const int*)d_in[1];
  const float* rw     = (const float*)d_in[2];
  const float* gup    = (const float*)d_in[3];
  const float* dwn    = (const float*)d_in[4];
  float* out = (float*)d_out;

  char* ws = (char*)d_ws;
  int*            cnt = (int*)ws;                                    // 16 B (pad to 1 KB)
  int*            tok = (int*)(ws + 1024);                           // NL*TT*4 = 32 KB
  float*          wgt = (float*)(ws + 1024 + NL*TT*4);               // 32 KB
  unsigned short* X   = (unsigned short*)(ws + 66560);               // NL*TT*HH*2 = 16 MB
  unsigned short* Hb  = (unsigned short*)(ws + 66560 + (size_t)NL*TT*HH*2); // NL*TT*FFN*2 = 32 MB

  k_zero  <<<2048, 256, 0, stream>>>(out, cnt);
  k_build <<<8,    256, 0, stream>>>(sel, rw, cnt, tok, wgt);
  k_gather<<<dim3(TT, NL), 128, 0, stream>>>(hidden, cnt, tok, X);
  k_gemm1 <<<dim3(FFN/64, TT/64, NL), 256, 0, stream>>>(X, gup, cnt, Hb);
  k_gemm2 <<<dim3(HH/64, TT/64, NL*SK), 256, 0, stream>>>(Hb, dwn, cnt, tok, wgt, out);
}